// Round 3
// baseline (98.892 us; speedup 1.0000x reference)
//
#include <hip/hip_runtime.h>
#include <math.h>

#define NC 5
#define EPS_F 0.1f
#define RPT 4  // rows per thread: 4 rows x 5 comps = 20 floats = 5 float4 -> perfect dwordx4

// Fast reciprocal: v_rcp_f32 (~1 ulp).
__device__ __forceinline__ float frcp(float v) { return __builtin_amdgcn_rcpf(v); }

// One thread = 4 consecutive rows, loaded/stored as 5 contiguous float4 each
// (16 B/lane coalescing on both read and write). Per row: q = x·Wᵀ + b,
// solve KL(softmax(t·log q) || uniform) = eps for t in (0,1], t=1 if feasible.
// f(t) = t·E_p[u] - log Z(t) + log n - eps, f'(t) = t·Var_p(u), u = s - max s.
__global__ __launch_bounds__(256) void klproj_kernel(
    const float4* __restrict__ x4,
    const float* __restrict__ W,
    const float* __restrict__ b,
    float4* __restrict__ out4,
    int nthreads)
{
    int i = blockIdx.x * blockDim.x + threadIdx.x;
    if (i >= nthreads) return;

    // --- vectorized load: 20 floats = 5 float4, contiguous per thread ---
    float4 L[5];
#pragma unroll
    for (int k = 0; k < 5; ++k) L[k] = x4[i * 5 + k];
    float* v = (float*)L;  // v[r*NC + j] = x[row r, comp j]

    const float C = 1.6094379124341003f - EPS_F;  // log(5) - eps

    float u[RPT][NC], t[RPT], lo[RPT], hi[RPT];
    bool infeas[RPT];

    // f, f' at t (divides via v_rcp; u^2 recomputed to save VGPRs)
    auto eval = [&](int r, float tt, float& f, float& fp) {
        float Z = 0.f, T1 = 0.f, T2 = 0.f;
#pragma unroll
        for (int j = 0; j < NC; ++j) {
            float uj = u[r][j];
            float ej = __expf(tt * uj);
            float eu = ej * uj;
            Z += ej;
            T1 += eu;
            T2 = fmaf(eu, uj, T2);
        }
        float rZ = frcp(Z);
        float Eu = T1 * rZ;
        f  = fmaf(tt, Eu, C - __logf(Z));
        fp = tt * fmaf(-Eu, Eu, T2 * rZ);
    };

    // --- setup + feasibility + smart init per row ---
    bool any = false;
#pragma unroll
    for (int r = 0; r < RPT; ++r) {
        float s[NC], m = -1e30f;
#pragma unroll
        for (int j = 0; j < NC; ++j) {
            float q = b[j];
#pragma unroll
            for (int k = 0; k < NC; ++k) q = fmaf(v[r * NC + k], W[j * NC + k], q);
            s[j] = __logf(q);
            m = fmaxf(m, s[j]);
        }
#pragma unroll
        for (int j = 0; j < NC; ++j) u[r][j] = s[j] - m;

        float f1, fp1;
        eval(r, 1.0f, f1, fp1);
        infeas[r] = (f1 > 0.f);
        lo[r] = 0.f; hi[r] = 1.f;
        // KL(p(t)||u) ~ KL1·t^2 near 0 => t0 = sqrt(eps/KL1)
        float t0 = 0.316227766017f * __frsqrt_rn(f1 + EPS_F);
        t[r] = (t0 > 0.f && t0 < 1.f) ? t0 : 0.5f;  // NaN/inf-safe
        any = any || infeas[r];
    }

    // --- bracketed Newton, 6 iterations; 4 independent chains for ILP ---
    if (any) {
#pragma unroll
        for (int it = 0; it < 6; ++it) {
#pragma unroll
            for (int r = 0; r < RPT; ++r) {
                float f, fp;
                eval(r, t[r], f, fp);
                bool pos = f > 0.f;
                hi[r] = pos ? t[r] : hi[r];
                lo[r] = pos ? lo[r] : t[r];
                float tn = t[r] - f * frcp(fp);
                t[r] = (tn > lo[r] && tn < hi[r]) ? tn : 0.5f * (lo[r] + hi[r]);
            }
        }
    }

    // --- final p = softmax(t·u), written back into the float4 buffer ---
#pragma unroll
    for (int r = 0; r < RPT; ++r) {
        float tf = infeas[r] ? t[r] : 1.0f;
        float e[NC], Z = 0.f;
#pragma unroll
        for (int j = 0; j < NC; ++j) { e[j] = __expf(tf * u[r][j]); Z += e[j]; }
        float rZ = frcp(Z);
#pragma unroll
        for (int j = 0; j < NC; ++j) v[r * NC + j] = e[j] * rZ;
    }

    // --- vectorized store: 5 contiguous float4 ---
#pragma unroll
    for (int k = 0; k < 5; ++k) out4[i * 5 + k] = L[k];
}

extern "C" void kernel_launch(void* const* d_in, const int* in_sizes, int n_in,
                              void* d_out, int out_size, void* d_ws, size_t ws_size,
                              hipStream_t stream) {
    const float* x = (const float*)d_in[0];
    const float* W = (const float*)d_in[1];
    const float* b = (const float*)d_in[2];
    float* out = (float*)d_out;
    int batch = in_sizes[0] / NC;          // 2,097,152 (divisible by 4)
    int nthreads = batch / RPT;

    int block = 256;
    int grid = (nthreads + block - 1) / block;
    klproj_kernel<<<grid, block, 0, stream>>>(
        (const float4*)x, W, b, (float4*)out, nthreads);
}

// Round 4
// 96.398 us; speedup vs baseline: 1.0259x; 1.0259x over previous
//
#include <hip/hip_runtime.h>
#include <math.h>

#define NC 5
#define EPS_F 0.1f

// Fast reciprocal: v_rcp_f32 (~1 ulp), avoids the 12-instruction precise-div
// sequence that dominated the round-1 critical path.
__device__ __forceinline__ float frcp(float v) { return __builtin_amdgcn_rcpf(v); }

// One thread handles TWO rows (i and i+half) for ILP: two independent
// Newton chains interleave in the scheduler. q = x·Wᵀ + b; solve
// KL(softmax(t·log q) || uniform) = eps for t in (0,1], t=1 if feasible.
// f(t) = t·E_p[u] - log Z(t) + log n - eps, f'(t) = t·Var_p(u), u = s - max s.
//
// Session finding (R1-R3): reported dur_us ≈ 84 µs harness restore fills
// (visible in rocprof as fillBufferAligned @ ~6.4 TB/s) + ~11-15 µs kernel,
// vs a 12.7 µs compulsory-traffic floor (80 MB @ 6.3 TB/s). Kernel-side
// changes (2x work reduction, dwordx4 vectorization, 4-way ILP) all moved
// the total by <5% — the kernel is at its HBM roofline.
__global__ __launch_bounds__(256) void klproj_kernel(
    const float* __restrict__ x,
    const float* __restrict__ W,
    const float* __restrict__ b,
    float* __restrict__ out,
    int half)
{
    int i = blockIdx.x * blockDim.x + threadIdx.x;
    if (i >= half) return;

    const float C = 1.6094379124341003f - EPS_F;   // log(5) - eps

    float u[2][NC], u2[2][NC], t[2], lo[2], hi[2], f1[2];

    // --- per-row setup: q, s = log q, u = s - max, u2 = u^2 ---
#pragma unroll
    for (int r = 0; r < 2; ++r) {
        int row = i + r * half;
        float xv[NC];
#pragma unroll
        for (int k = 0; k < NC; ++k) xv[k] = x[row * NC + k];
        float s[NC];
        float m = -1e30f;
#pragma unroll
        for (int j = 0; j < NC; ++j) {
            float q = b[j];
#pragma unroll
            for (int k = 0; k < NC; ++k) q = fmaf(xv[k], W[j * NC + k], q);
            s[j] = __logf(q);
            m = fmaxf(m, s[j]);
        }
#pragma unroll
        for (int j = 0; j < NC; ++j) {
            u[r][j]  = s[j] - m;
            u2[r][j] = u[r][j] * u[r][j];
        }
    }

    // f, f' at a given t (all divides via v_rcp)
    auto eval = [&](int r, float tt, float& f, float& fp) {
        float Z = 0.f, T1 = 0.f, T2 = 0.f;
#pragma unroll
        for (int j = 0; j < NC; ++j) {
            float ej = __expf(tt * u[r][j]);
            Z += ej;
            T1 = fmaf(ej, u[r][j], T1);
            T2 = fmaf(ej, u2[r][j], T2);
        }
        float rZ = frcp(Z);
        float Eu = T1 * rZ;
        f  = fmaf(tt, Eu, C - __logf(Z));
        fp = tt * fmaf(-Eu, Eu, T2 * rZ);
    };

    // --- feasibility at t=1 + smart init t0 = sqrt(eps/KL1) (KL ~ KL1·t²) ---
    bool any = false;
#pragma unroll
    for (int r = 0; r < 2; ++r) {
        float fp1;
        eval(r, 1.0f, f1[r], fp1);
        lo[r] = 0.f; hi[r] = 1.f;
        float kl1 = f1[r] + EPS_F;                  // = KL(p(1)||u) >= 0
        float t0  = 0.316227766017f * __frsqrt_rn(kl1);  // sqrt(eps/KL1)
        t[r] = (t0 > 0.f && t0 < 1.f) ? t0 : 0.5f;  // NaN/inf-safe guard
        any = any || (f1[r] > 0.f);
    }

    // --- bracketed Newton, 6 iterations (skipped by fully-feasible waves) ---
    if (any) {
#pragma unroll
        for (int it = 0; it < 6; ++it) {
#pragma unroll
            for (int r = 0; r < 2; ++r) {
                float f, fp;
                eval(r, t[r], f, fp);
                bool pos = f > 0.f;
                hi[r] = pos ? t[r] : hi[r];
                lo[r] = pos ? lo[r] : t[r];
                float tn = t[r] - f * frcp(fp);
                t[r] = (tn > lo[r] && tn < hi[r]) ? tn : 0.5f * (lo[r] + hi[r]);
            }
        }
    }

    // --- final p = softmax(t·u); exact t=1 for feasible rows ---
#pragma unroll
    for (int r = 0; r < 2; ++r) {
        float tf = (f1[r] > 0.f) ? t[r] : 1.0f;
        float e[NC], Z = 0.f;
#pragma unroll
        for (int j = 0; j < NC; ++j) { e[j] = __expf(tf * u[r][j]); Z += e[j]; }
        float rZ = frcp(Z);
        int row = i + r * half;
#pragma unroll
        for (int j = 0; j < NC; ++j) out[row * NC + j] = e[j] * rZ;
    }
}

extern "C" void kernel_launch(void* const* d_in, const int* in_sizes, int n_in,
                              void* d_out, int out_size, void* d_ws, size_t ws_size,
                              hipStream_t stream) {
    const float* x = (const float*)d_in[0];
    const float* W = (const float*)d_in[1];
    const float* b = (const float*)d_in[2];
    float* out = (float*)d_out;
    int batch = in_sizes[0] / NC;
    int half = batch / 2;

    int block = 256;
    int grid = (half + block - 1) / block;
    klproj_kernel<<<grid, block, 0, stream>>>(x, W, b, out, half);
}